// Round 3
// baseline (2297.699 us; speedup 1.0000x reference)
//
#include <hip/hip_runtime.h>

typedef unsigned short u16;
typedef unsigned int u32;
typedef __bf16 bf16x8 __attribute__((ext_vector_type(8)));
typedef float f32x4 __attribute__((ext_vector_type(4)));
typedef u32 u32x4 __attribute__((ext_vector_type(4)));

__device__ __forceinline__ float b2f(u16 s) { return __uint_as_float((u32)s << 16); }
__device__ __forceinline__ u16 f2bf(float f) {
    u32 u = __float_as_uint(f);
    u += 0x7FFFu + ((u >> 16) & 1u);   // RNE
    return (u16)(u >> 16);
}
__device__ __forceinline__ u32 pack2(float lo, float hi) {
    return (u32)f2bf(lo) | ((u32)f2bf(hi) << 16);
}
__device__ __forceinline__ float bflo(u32 u) { return __uint_as_float(u << 16); }
__device__ __forceinline__ float bfhi(u32 u) { return __uint_as_float(u & 0xFFFF0000u); }

// async global->LDS, 16B per lane, LDS dest = wave-uniform base + lane*16
__device__ __forceinline__ void gll16(const void* gp, void* lp) {
    __builtin_amdgcn_global_load_lds(
        (__attribute__((address_space(1))) void*)(void*)gp,
        (__attribute__((address_space(3))) void*)lp, 16, 0, 0);
}

// ---------------------------------------------------------------------------
// fp32 -> bf16 conversion pre-pass: x (33.5M) + 4 weights (4.2M each).
// blockIdx.y selects the tensor; grid-stride by 8 elements per thread.
// ---------------------------------------------------------------------------
__global__ __launch_bounds__(256) void cvt5(const float* __restrict__ x,
                                            const float* __restrict__ wq,
                                            const float* __restrict__ wk,
                                            const float* __restrict__ wv,
                                            const float* __restrict__ wo,
                                            u16* __restrict__ xb, u16* __restrict__ wb) {
    const float* src;
    u16* dst;
    int n;
    const int DD = 2048 * 2048;
    switch (blockIdx.y) {
        case 0: src = x;  dst = xb;          n = 16384 * 2048; break;
        case 1: src = wq; dst = wb;          n = DD; break;
        case 2: src = wk; dst = wb + DD;     n = DD; break;
        case 3: src = wv; dst = wb + 2 * DD; n = DD; break;
        default: src = wo; dst = wb + 3 * DD; n = DD; break;
    }
    const int n8 = n >> 3;
    for (int i = blockIdx.x * 256 + threadIdx.x; i < n8; i += gridDim.x * 256) {
        float4 a = ((const float4*)src)[i * 2];
        float4 b = ((const float4*)src)[i * 2 + 1];
        uint4 o;
        o.x = pack2(a.x, a.y);
        o.y = pack2(a.z, a.w);
        o.z = pack2(b.x, b.y);
        o.w = pack2(b.z, b.w);
        ((uint4*)dst)[i] = o;
    }
}

// ---------------------------------------------------------------------------
// GEMM: C[m,n] = sum_k A[m,k] * W[n,k] + bias[n], M=16384, N=K=2048, A/W bf16.
// m97 structure: 128x128 tile, BK=64, global_load_lds w16, 4 waves 2x2, 4x4 MFMA acc.
// DO_ROPE (CT=u16): RoPE over (d, d+32) pairs within each 64-wide head; pos = row & 4095.
// CT=float: plain epilogue writing fp32 (final output).
// ---------------------------------------------------------------------------
template <typename CT, bool DO_ROPE>
__device__ __forceinline__ void gemm_body(const u16* __restrict__ A, const u16* __restrict__ W,
                                          const float* __restrict__ bias, CT* __restrict__ C) {
    constexpr int K = 2048;
    __shared__ __align__(16) u16 As[128 * 64];
    __shared__ __align__(16) u16 Bs[128 * 64];
    const int tid = threadIdx.x;
    const int w = tid >> 6, lane = tid & 63;
    const int l15 = lane & 15, quad = lane >> 4;
    const int wm = (w >> 1) * 64, wn = (w & 1) * 64;
    const int row0 = blockIdx.y * 128, col0 = blockIdx.x * 128;

    f32x4 acc[4][4] = {};

    // staging: wave w loads rows [w*32, w*32+32) of each 128x64 tile (4 calls of 1KB each)
    const u16* Ag = A + (size_t)(row0 + w * 32 + (lane >> 3)) * K + (lane & 7) * 8;
    const u16* Wg = W + (size_t)(col0 + w * 32 + (lane >> 3)) * K + (lane & 7) * 8;
    u16* AsW = &As[w * 2048];
    u16* BsW = &Bs[w * 2048];

    for (int kt = 0; kt < K; kt += 64) {
#pragma unroll
        for (int c = 0; c < 4; ++c) {
            gll16(Ag + (size_t)c * 8 * K + kt, AsW + c * 512);
            gll16(Wg + (size_t)c * 8 * K + kt, BsW + c * 512);
        }
        __syncthreads();
#pragma unroll
        for (int kk = 0; kk < 64; kk += 32) {
            bf16x8 af[4], bfr[4];
#pragma unroll
            for (int mi = 0; mi < 4; mi++)
                af[mi] = *(const bf16x8*)&As[(wm + mi * 16 + l15) * 64 + kk + quad * 8];
#pragma unroll
            for (int ni = 0; ni < 4; ni++)
                bfr[ni] = *(const bf16x8*)&Bs[(wn + ni * 16 + l15) * 64 + kk + quad * 8];
#pragma unroll
            for (int mi = 0; mi < 4; mi++)
#pragma unroll
                for (int ni = 0; ni < 4; ni++)
                    acc[mi][ni] = __builtin_amdgcn_mfma_f32_16x16x32_bf16(af[mi], bfr[ni],
                                                                          acc[mi][ni], 0, 0, 0);
        }
        __syncthreads();
    }

    // epilogue: C/D layout col = lane&15, row = quad*4 + reg (verified m89)
    float bb[4];
#pragma unroll
    for (int ni = 0; ni < 4; ni++) bb[ni] = bias[col0 + wn + ni * 16 + l15];

    if constexpr (DO_ROPE) {
        // within-head dim d = t*16 + l15 (t in {0,1}); partner d+32 is reg ni=t+2 (same lane)
        // theta_d / (2*pi), d = t*16+l15; 10000^(-d/32) = 2^(-d*log2(1e4)/32)
        float invr[2];
#pragma unroll
        for (int t = 0; t < 2; t++)
            invr[t] = exp2f((float)(t * 16 + l15) * -0.41524101186092030f) *
                      0.15915494309189535f;
#pragma unroll
        for (int mi = 0; mi < 4; mi++) {
#pragma unroll
            for (int r = 0; r < 4; r++) {
                const int rg = row0 + wm + mi * 16 + quad * 4 + r;
                const float pos = (float)(rg & 4095);
                u16* Cr = (u16*)C + (size_t)rg * 2048 + col0 + wn + l15;
#pragma unroll
                for (int t = 0; t < 2; t++) {
                    float rev = pos * invr[t];
                    rev -= floorf(rev);                      // reduce to [0,1) revolutions
                    const float ang = rev * 6.28318530717958647f;
                    const float sn = __sinf(ang), cs = __cosf(ang);
                    const float x1 = acc[mi][t][r] + bb[t];
                    const float x2 = acc[mi][t + 2][r] + bb[t + 2];
                    Cr[t * 16] = f2bf(x1 * cs - x2 * sn);
                    Cr[(t + 2) * 16] = f2bf(x2 * cs + x1 * sn);
                }
            }
        }
    } else {
#pragma unroll
        for (int mi = 0; mi < 4; mi++) {
#pragma unroll
            for (int r = 0; r < 4; r++) {
                const int rg = row0 + wm + mi * 16 + quad * 4 + r;
                CT* Cr = C + (size_t)rg * 2048 + col0 + wn + l15;
#pragma unroll
                for (int ni = 0; ni < 4; ni++) {
                    const float val = acc[mi][ni][r] + bb[ni];
                    if constexpr (sizeof(CT) == 2)
                        Cr[ni * 16] = f2bf(val);
                    else
                        Cr[ni * 16] = val;
                }
            }
        }
    }
}

__global__ __launch_bounds__(256, 3) void qkv_gemm(const u16* __restrict__ x,
                                                   const u16* __restrict__ wb,
                                                   const float* __restrict__ bq,
                                                   const float* __restrict__ bk,
                                                   const float* __restrict__ bv,
                                                   u16* q, u16* k, u16* v) {
    const int z = blockIdx.z;
    const int DD = 2048 * 2048;
    const u16* W = wb + (size_t)z * DD;
    const float* b = (z == 0) ? bq : ((z == 1) ? bk : bv);
    u16* C = (z == 0) ? q : ((z == 1) ? k : v);
    if (z < 2)
        gemm_body<u16, true>(x, W, b, C);
    else
        gemm_body<u16, false>(x, W, b, C);
}

__global__ __launch_bounds__(256, 3) void out_gemm(const u16* __restrict__ A,
                                                   const u16* __restrict__ W,
                                                   const float* __restrict__ b,
                                                   float* __restrict__ C) {
    gemm_body<float, false>(A, W, b, C);
}

// ---------------------------------------------------------------------------
// Attention over the heads axis: per (b,l) a 32x32 causal softmax over H with Hd=64.
// One wave per (b,l). K,V staged via normal per-lane 16B loads (TCP-coalesced)
// -> registers -> ds_write_b128 (NOT global_load_lds); all streaming global
// accesses nontemporal. LDS wave-private -> no __syncthreads.
// Output: transpose 32x64 tile through dead ks[w] (XOR swizzle), then 4 store
// insts x 8 full 128-B lines. Layout: row = b*4096+h*128+l/32, col=(l%32)*64+d.
// ---------------------------------------------------------------------------
#define ACC8(base, v4)                                           \
    o[base + 0] += p * bflo(v4[0]); o[base + 1] += p * bfhi(v4[0]); \
    o[base + 2] += p * bflo(v4[1]); o[base + 3] += p * bfhi(v4[1]); \
    o[base + 4] += p * bflo(v4[2]); o[base + 5] += p * bfhi(v4[2]); \
    o[base + 6] += p * bflo(v4[3]); o[base + 7] += p * bfhi(v4[3]);

__global__ __launch_bounds__(256, 3) void attn_heads(const u16* __restrict__ Q,
                                                     const u16* __restrict__ Kx,
                                                     const u16* __restrict__ V,
                                                     u16* __restrict__ O) {
    __shared__ __align__(16) u16 ks[4][2048];
    __shared__ __align__(16) u16 vs[4][2048];
    __shared__ __align__(16) u16 ps[4][1024];  // probs bf16, [g][h] (transposed)
    const int tid = threadIdx.x;
    const int w = tid >> 6, lane = tid & 63;
    const int u = blockIdx.x * 4 + w;  // (b,l) index
    const int b = u >> 12, pos = u & 4095;
    const int h = lane & 31, ch = lane >> 5;

    // ---- global loads: normal vector loads through TCP coalescer, nt hint ----
    const u16* kg = Kx + (size_t)u * 2048;
    const u16* vg = V + (size_t)u * 2048;
    const u16* qg = Q + (size_t)u * 2048 + h * 64;
    u32x4 kv[4], vv[4], qraw[8];
#pragma unroll
    for (int c = 0; c < 4; ++c)
        kv[c] = __builtin_nontemporal_load((const u32x4*)(kg + c * 512 + lane * 8));
#pragma unroll
    for (int c = 0; c < 4; ++c)
        vv[c] = __builtin_nontemporal_load((const u32x4*)(vg + c * 512 + lane * 8));
#pragma unroll
    for (int c = 0; c < 8; ++c)
        qraw[c] = __builtin_nontemporal_load((const u32x4*)(qg + c * 8));

    // ---- stage K,V to wave-private LDS (ds_write_b128, no barrier needed) ----
#pragma unroll
    for (int c = 0; c < 4; ++c) *(u32x4*)&ks[w][c * 512 + lane * 8] = kv[c];
#pragma unroll
    for (int c = 0; c < 4; ++c) *(u32x4*)&vs[w][c * 512 + lane * 8] = vv[c];
    asm volatile("s_waitcnt lgkmcnt(0)" ::: "memory");

    // scores: lane computes s[h][g] for g in [ch*16, ch*16+16)
    float s[16];
#pragma unroll
    for (int t = 0; t < 16; t++) s[t] = 0.f;
#pragma unroll
    for (int cc = 0; cc < 8; ++cc) {
        const u32x4 qc = qraw[cc];
        const float q0 = bflo(qc[0]), q1 = bfhi(qc[0]), q2 = bflo(qc[1]), q3 = bfhi(qc[1]);
        const float q4 = bflo(qc[2]), q5 = bfhi(qc[2]), q6 = bflo(qc[3]), q7 = bfhi(qc[3]);
        const u16* kr = &ks[w][ch * 1024 + cc * 8];
#pragma unroll
        for (int t = 0; t < 16; t++) {
            const u32x4 kc = *(const u32x4*)(kr + t * 64);  // 2 distinct addrs -> broadcast
            s[t] += q0 * bflo(kc[0]) + q1 * bfhi(kc[0]) + q2 * bflo(kc[1]) + q3 * bfhi(kc[1]) +
                    q4 * bflo(kc[2]) + q5 * bfhi(kc[2]) + q6 * bflo(kc[3]) + q7 * bfhi(kc[3]);
        }
    }
    // causal mask + softmax over g (row h split across lanes l and l^32)
    float mx = -1e30f;
#pragma unroll
    for (int t = 0; t < 16; t++) {
        const int g = ch * 16 + t;
        s[t] = (g <= h) ? s[t] * 0.125f : -1e9f;
        mx = fmaxf(mx, s[t]);
    }
    mx = fmaxf(mx, __shfl_xor(mx, 32));
    float sum = 0.f;
#pragma unroll
    for (int t = 0; t < 16; t++) {
        s[t] = __expf(s[t] - mx);
        sum += s[t];
    }
    sum += __shfl_xor(sum, 32);
    const float inv = 1.f / sum;
#pragma unroll
    for (int t = 0; t < 16; t++) ps[w][(ch * 16 + t) * 32 + h] = f2bf(s[t] * inv);
    asm volatile("s_waitcnt lgkmcnt(0)" ::: "memory");

    // PV: lane computes out[h][dbase..dbase+32)
    float o[32];
#pragma unroll
    for (int t = 0; t < 32; t++) o[t] = 0.f;
    const int dbase = ch * 32;
#pragma unroll
    for (int g = 0; g < 32; ++g) {
        const float p = b2f(ps[w][g * 32 + h]);
        const u16* vrow = &vs[w][g * 64 + dbase];
        const u32x4 va = *(const u32x4*)(vrow);
        const u32x4 vb = *(const u32x4*)(vrow + 8);
        const u32x4 vc = *(const u32x4*)(vrow + 16);
        const u32x4 vd = *(const u32x4*)(vrow + 24);
        ACC8(0, va) ACC8(8, vb) ACC8(16, vc) ACC8(24, vd)
    }

    // ---- coalesced store epilogue ----
    // ks[w] is dead (scores done): reuse as os[32 rows][64 cols] u16, with the
    // 16B-chunk index XOR-swizzled by (row&7) for conflict-free b128 access.
    u16* os = &ks[w][0];
#pragma unroll
    for (int j = 0; j < 4; ++j) {
        u32x4 t;
        t[0] = pack2(o[j * 8 + 0], o[j * 8 + 1]);
        t[1] = pack2(o[j * 8 + 2], o[j * 8 + 3]);
        t[2] = pack2(o[j * 8 + 4], o[j * 8 + 5]);
        t[3] = pack2(o[j * 8 + 6], o[j * 8 + 7]);
        // logical chunk (ch*4+j) of row h, stored at chunk ((ch*4+j)^(h&7))
        *(u32x4*)&os[h * 64 + (((ch * 4 + j) ^ (h & 7)) * 8)] = t;
    }
    asm volatile("s_waitcnt lgkmcnt(0)" ::: "memory");

    // 4 store insts; inst c: 8-lane group r writes row hh=c*8+r, lane j holds
    // logical chunk j (LDS chunk j^r since hh&7==r) -> one full 128B line per group.
    const int r = lane >> 3, j = lane & 7;
    const size_t obase = ((size_t)b * 4096 + (pos >> 5)) * 2048 + (size_t)(pos & 31) * 64 +
                         (size_t)j * 8;
#pragma unroll
    for (int c = 0; c < 4; ++c) {
        const int hh = c * 8 + r;
        const u32x4 t = *(const u32x4*)&os[hh * 64 + ((j ^ r) * 8)];
        __builtin_nontemporal_store(t, (u32x4*)(O + obase + (size_t)hh * (128 * 2048)));
    }
}

extern "C" void kernel_launch(void* const* d_in, const int* in_sizes, int n_in,
                              void* d_out, int out_size, void* d_ws, size_t ws_size,
                              hipStream_t stream) {
    const float* x = (const float*)d_in[0];
    const float* Wq = (const float*)d_in[1];
    const float* bq = (const float*)d_in[2];
    const float* Wk = (const float*)d_in[3];
    const float* bk = (const float*)d_in[4];
    const float* Wv = (const float*)d_in[5];
    const float* bv = (const float*)d_in[6];
    const float* Wo = (const float*)d_in[7];
    const float* bo = (const float*)d_in[8];

    const size_t MN = (size_t)16384 * 2048;
    const size_t DD = (size_t)2048 * 2048;
    u16* ws = (u16*)d_ws;
    u16* xb = ws;            // bf16 x; reused as attention output after qkv_gemm
    u16* q = ws + MN;
    u16* k = ws + 2 * MN;
    u16* v = ws + 3 * MN;
    u16* wb = ws + 4 * MN;   // 4 bf16 weight matrices, DD each
    u16* ao = xb;            // alias: xb dead after qkv_gemm
    float* out = (float*)d_out;

    dim3 blk(256, 1, 1);
    hipLaunchKernelGGL(cvt5, dim3(4096, 5, 1), blk, 0, stream, x, Wq, Wk, Wv, Wo, xb, wb);
    hipLaunchKernelGGL(qkv_gemm, dim3(16, 128, 3), blk, 0, stream,
                       xb, wb, bq, bk, bv, q, k, v);
    hipLaunchKernelGGL(attn_heads, dim3(4096, 1, 1), blk, 0, stream, q, k, v, ao);
    hipLaunchKernelGGL(out_gemm, dim3(16, 128, 1), blk, 0, stream, ao, wb + 3 * DD, bo, out);
}

// Round 4
// 1872.442 us; speedup vs baseline: 1.2271x; 1.2271x over previous
//
#include <hip/hip_runtime.h>

typedef unsigned short u16;
typedef unsigned int u32;
typedef __bf16 bf16x8 __attribute__((ext_vector_type(8)));
typedef float f32x4 __attribute__((ext_vector_type(4)));

__device__ __forceinline__ float b2f(u16 s) { return __uint_as_float((u32)s << 16); }
__device__ __forceinline__ u16 f2bf(float f) {
    u32 u = __float_as_uint(f);
    u += 0x7FFFu + ((u >> 16) & 1u);   // RNE
    return (u16)(u >> 16);
}
__device__ __forceinline__ u32 pack2(float lo, float hi) {
    return (u32)f2bf(lo) | ((u32)f2bf(hi) << 16);
}
__device__ __forceinline__ float bflo(u32 u) { return __uint_as_float(u << 16); }
__device__ __forceinline__ float bfhi(u32 u) { return __uint_as_float(u & 0xFFFF0000u); }

// async global->LDS, 16B per lane, LDS dest = wave-uniform base + lane*16.
// NOTE: the GLOBAL source address is per-lane (gather allowed).
__device__ __forceinline__ void gll16(const void* gp, void* lp) {
    __builtin_amdgcn_global_load_lds(
        (__attribute__((address_space(1))) void*)(void*)gp,
        (__attribute__((address_space(3))) void*)lp, 16, 0, 0);
}

// ---------------------------------------------------------------------------
// fp32 -> bf16 conversion pre-pass: x (33.5M) + 4 weights (4.2M each).
// blockIdx.y selects the tensor; grid-stride by 8 elements per thread.
// ---------------------------------------------------------------------------
__global__ __launch_bounds__(256) void cvt5(const float* __restrict__ x,
                                            const float* __restrict__ wq,
                                            const float* __restrict__ wk,
                                            const float* __restrict__ wv,
                                            const float* __restrict__ wo,
                                            u16* __restrict__ xb, u16* __restrict__ wb) {
    const float* src;
    u16* dst;
    int n;
    const int DD = 2048 * 2048;
    switch (blockIdx.y) {
        case 0: src = x;  dst = xb;          n = 16384 * 2048; break;
        case 1: src = wq; dst = wb;          n = DD; break;
        case 2: src = wk; dst = wb + DD;     n = DD; break;
        case 3: src = wv; dst = wb + 2 * DD; n = DD; break;
        default: src = wo; dst = wb + 3 * DD; n = DD; break;
    }
    const int n8 = n >> 3;
    for (int i = blockIdx.x * 256 + threadIdx.x; i < n8; i += gridDim.x * 256) {
        float4 a = ((const float4*)src)[i * 2];
        float4 b = ((const float4*)src)[i * 2 + 1];
        uint4 o;
        o.x = pack2(a.x, a.y);
        o.y = pack2(a.z, a.w);
        o.z = pack2(b.x, b.y);
        o.w = pack2(b.z, b.w);
        ((uint4*)dst)[i] = o;
    }
}

// ---------------------------------------------------------------------------
// GEMM: C[m,n] = sum_k A[m,k] * W[n,k] + bias[n], M=16384, N=K=2048, A/W bf16.
// m97 structure: 128x128 tile, BK=64, global_load_lds w16, 4 waves 2x2, 4x4 MFMA acc.
// DO_ROPE (CT=u16): RoPE over (d, d+32) pairs within each 64-wide head; pos = row & 4095.
// GATHER_A: A is stored in NATURAL attention-output layout ao[u = b*4096+l][h*64+d];
//   logical (scrambled) row m = b*4096 + h*128 + (l>>5), col = (l&31)*64 + d.
//   Staging gathers per-lane 128-B segments: u_nat = (m>>12)*4096 + (m&127)*32 + kt/64,
//   j = ((m>>7)&31)*64 + (lane&7)*8. LDS layout after staging is identical to linear.
// ---------------------------------------------------------------------------
template <typename CT, bool DO_ROPE, bool GATHER_A>
__device__ __forceinline__ void gemm_body(const u16* __restrict__ A, const u16* __restrict__ W,
                                          const float* __restrict__ bias, CT* __restrict__ C) {
    constexpr int K = 2048;
    __shared__ __align__(16) u16 As[128 * 64];
    __shared__ __align__(16) u16 Bs[128 * 64];
    const int tid = threadIdx.x;
    const int w = tid >> 6, lane = tid & 63;
    const int l15 = lane & 15, quad = lane >> 4;
    const int wm = (w >> 1) * 64, wn = (w & 1) * 64;
    const int row0 = blockIdx.y * 128, col0 = blockIdx.x * 128;

    f32x4 acc[4][4] = {};

    // staging: wave w loads rows [w*32, w*32+32) of each 128x64 tile (4 calls of 1KB each)
    const u16* Ag = A + (size_t)(row0 + w * 32 + (lane >> 3)) * K + (lane & 7) * 8;
    const u16* Wg = W + (size_t)(col0 + w * 32 + (lane >> 3)) * K + (lane & 7) * 8;
    // gather base pointers for GATHER_A (kt-invariant part), one per staging call c
    const u16* AgG[4];
    if constexpr (GATHER_A) {
#pragma unroll
        for (int c = 0; c < 4; ++c) {
            const int m = row0 + w * 32 + c * 8 + (lane >> 3);
            const size_t u_nat0 = (size_t)(m >> 12) * 4096 + (size_t)(m & 127) * 32;
            const int j = ((m >> 7) & 31) * 64 + (lane & 7) * 8;
            AgG[c] = A + u_nat0 * 2048 + j;
        }
    }
    u16* AsW = &As[w * 2048];
    u16* BsW = &Bs[w * 2048];

    for (int kt = 0; kt < K; kt += 64) {
#pragma unroll
        for (int c = 0; c < 4; ++c) {
            if constexpr (GATHER_A)
                gll16(AgG[c] + (size_t)(kt >> 6) * 2048, AsW + c * 512);
            else
                gll16(Ag + (size_t)c * 8 * K + kt, AsW + c * 512);
            gll16(Wg + (size_t)c * 8 * K + kt, BsW + c * 512);
        }
        __syncthreads();
#pragma unroll
        for (int kk = 0; kk < 64; kk += 32) {
            bf16x8 af[4], bfr[4];
#pragma unroll
            for (int mi = 0; mi < 4; mi++)
                af[mi] = *(const bf16x8*)&As[(wm + mi * 16 + l15) * 64 + kk + quad * 8];
#pragma unroll
            for (int ni = 0; ni < 4; ni++)
                bfr[ni] = *(const bf16x8*)&Bs[(wn + ni * 16 + l15) * 64 + kk + quad * 8];
#pragma unroll
            for (int mi = 0; mi < 4; mi++)
#pragma unroll
                for (int ni = 0; ni < 4; ni++)
                    acc[mi][ni] = __builtin_amdgcn_mfma_f32_16x16x32_bf16(af[mi], bfr[ni],
                                                                          acc[mi][ni], 0, 0, 0);
        }
        __syncthreads();
    }

    // epilogue: C/D layout col = lane&15, row = quad*4 + reg (verified m89)
    float bb[4];
#pragma unroll
    for (int ni = 0; ni < 4; ni++) bb[ni] = bias[col0 + wn + ni * 16 + l15];

    if constexpr (DO_ROPE) {
        // within-head dim d = t*16 + l15 (t in {0,1}); partner d+32 is reg ni=t+2 (same lane)
        // theta_d / (2*pi), d = t*16+l15; 10000^(-d/32) = 2^(-d*log2(1e4)/32)
        float invr[2];
#pragma unroll
        for (int t = 0; t < 2; t++)
            invr[t] = exp2f((float)(t * 16 + l15) * -0.41524101186092030f) *
                      0.15915494309189535f;
#pragma unroll
        for (int mi = 0; mi < 4; mi++) {
#pragma unroll
            for (int r = 0; r < 4; r++) {
                const int rg = row0 + wm + mi * 16 + quad * 4 + r;
                const float pos = (float)(rg & 4095);
                u16* Cr = (u16*)C + (size_t)rg * 2048 + col0 + wn + l15;
#pragma unroll
                for (int t = 0; t < 2; t++) {
                    float rev = pos * invr[t];
                    rev -= floorf(rev);                      // reduce to [0,1) revolutions
                    const float ang = rev * 6.28318530717958647f;
                    const float sn = __sinf(ang), cs = __cosf(ang);
                    const float x1 = acc[mi][t][r] + bb[t];
                    const float x2 = acc[mi][t + 2][r] + bb[t + 2];
                    Cr[t * 16] = f2bf(x1 * cs - x2 * sn);
                    Cr[(t + 2) * 16] = f2bf(x2 * cs + x1 * sn);
                }
            }
        }
    } else {
#pragma unroll
        for (int mi = 0; mi < 4; mi++) {
#pragma unroll
            for (int r = 0; r < 4; r++) {
                const int rg = row0 + wm + mi * 16 + quad * 4 + r;
                CT* Cr = C + (size_t)rg * 2048 + col0 + wn + l15;
#pragma unroll
                for (int ni = 0; ni < 4; ni++) {
                    const float val = acc[mi][ni][r] + bb[ni];
                    if constexpr (sizeof(CT) == 2)
                        Cr[ni * 16] = f2bf(val);
                    else
                        Cr[ni * 16] = val;
                }
            }
        }
    }
}

__global__ __launch_bounds__(256, 3) void qkv_gemm(const u16* __restrict__ x,
                                                   const u16* __restrict__ wb,
                                                   const float* __restrict__ bq,
                                                   const float* __restrict__ bk,
                                                   const float* __restrict__ bv,
                                                   u16* q, u16* k, u16* v) {
    const int z = blockIdx.z;
    const int DD = 2048 * 2048;
    const u16* W = wb + (size_t)z * DD;
    const float* b = (z == 0) ? bq : ((z == 1) ? bk : bv);
    u16* C = (z == 0) ? q : ((z == 1) ? k : v);
    if (z < 2)
        gemm_body<u16, true, false>(x, W, b, C);
    else
        gemm_body<u16, false, false>(x, W, b, C);
}

__global__ __launch_bounds__(256, 3) void out_gemm(const u16* __restrict__ A,
                                                   const u16* __restrict__ W,
                                                   const float* __restrict__ b,
                                                   float* __restrict__ C) {
    gemm_body<float, false, true>(A, W, b, C);
}

// ---------------------------------------------------------------------------
// Attention over the heads axis: per (b,l) a 32x32 causal softmax over H with Hd=64.
// One wave per (b,l). K,V staged to LDS via global_load_lds; Q row per lane in regs.
// Output written in NATURAL layout ao[u][h*64+d]: each wave stores its own 4-KB
// row contiguously (full lines, single writer, one XCD) — the transpose-scramble
// is absorbed into out_gemm's gather staging.
// ---------------------------------------------------------------------------
#define ACC8(base, v4)                                       \
    o[base + 0] += p * bflo(v4.x); o[base + 1] += p * bfhi(v4.x); \
    o[base + 2] += p * bflo(v4.y); o[base + 3] += p * bfhi(v4.y); \
    o[base + 4] += p * bflo(v4.z); o[base + 5] += p * bfhi(v4.z); \
    o[base + 6] += p * bflo(v4.w); o[base + 7] += p * bfhi(v4.w);

__global__ __launch_bounds__(256, 3) void attn_heads(const u16* __restrict__ Q,
                                                     const u16* __restrict__ Kx,
                                                     const u16* __restrict__ V,
                                                     u16* __restrict__ O) {
    __shared__ __align__(16) u16 ks[4][2048];
    __shared__ __align__(16) u16 vs[4][2048];
    __shared__ __align__(16) u16 ps[4][1024];  // probs bf16, [g][h] (transposed)
    const int tid = threadIdx.x;
    const int w = tid >> 6, lane = tid & 63;
    const int u = blockIdx.x * 4 + w;  // (b,l) index
    const int h = lane & 31, ch = lane >> 5;

    // stage K, V (row-major [32][64] bf16 = 4KB each = 4 calls of 1KB)
    const u16* kg = Kx + (size_t)u * 2048;
    const u16* vg = V + (size_t)u * 2048;
#pragma unroll
    for (int c = 0; c < 4; ++c) {
        gll16(kg + c * 512 + lane * 8, &ks[w][c * 512]);
        gll16(vg + c * 512 + lane * 8, &vs[w][c * 512]);
    }
    // Q row for this lane -> registers (lanes l and l+32 duplicate; L1 absorbs)
    const u16* qg = Q + (size_t)u * 2048 + h * 64;
    uint4 qraw[8];
#pragma unroll
    for (int c = 0; c < 8; ++c) qraw[c] = *(const uint4*)(qg + c * 8);
    __syncthreads();  // drains vmcnt for global_load_lds

    // scores: lane computes s[h][g] for g in [ch*16, ch*16+16)
    float s[16];
#pragma unroll
    for (int t = 0; t < 16; t++) s[t] = 0.f;
#pragma unroll
    for (int cc = 0; cc < 8; ++cc) {
        const uint4 qc = qraw[cc];
        const float q0 = bflo(qc.x), q1 = bfhi(qc.x), q2 = bflo(qc.y), q3 = bfhi(qc.y);
        const float q4 = bflo(qc.z), q5 = bfhi(qc.z), q6 = bflo(qc.w), q7 = bfhi(qc.w);
        const u16* kr = &ks[w][ch * 1024 + cc * 8];
#pragma unroll
        for (int t = 0; t < 16; t++) {
            const uint4 kc = *(const uint4*)(kr + t * 64);  // 2 distinct addrs -> broadcast
            s[t] += q0 * bflo(kc.x) + q1 * bfhi(kc.x) + q2 * bflo(kc.y) + q3 * bfhi(kc.y) +
                    q4 * bflo(kc.z) + q5 * bfhi(kc.z) + q6 * bflo(kc.w) + q7 * bfhi(kc.w);
        }
    }
    // causal mask + softmax over g (row h split across lanes l and l^32)
    float mx = -1e30f;
#pragma unroll
    for (int t = 0; t < 16; t++) {
        const int g = ch * 16 + t;
        s[t] = (g <= h) ? s[t] * 0.125f : -1e9f;
        mx = fmaxf(mx, s[t]);
    }
    mx = fmaxf(mx, __shfl_xor(mx, 32));
    float sum = 0.f;
#pragma unroll
    for (int t = 0; t < 16; t++) {
        s[t] = __expf(s[t] - mx);
        sum += s[t];
    }
    sum += __shfl_xor(sum, 32);
    const float inv = 1.f / sum;
#pragma unroll
    for (int t = 0; t < 16; t++) ps[w][(ch * 16 + t) * 32 + h] = f2bf(s[t] * inv);
    __syncthreads();

    // PV: lane computes out[h][dbase..dbase+32)
    float o[32];
#pragma unroll
    for (int t = 0; t < 32; t++) o[t] = 0.f;
    const int dbase = ch * 32;
#pragma unroll
    for (int g = 0; g < 32; ++g) {
        const float p = b2f(ps[w][g * 32 + h]);
        const u16* vrow = &vs[w][g * 64 + dbase];
        const uint4 va = *(const uint4*)(vrow);
        const uint4 vb = *(const uint4*)(vrow + 8);
        const uint4 vc = *(const uint4*)(vrow + 16);
        const uint4 vd = *(const uint4*)(vrow + 24);
        ACC8(0, va) ACC8(8, vb) ACC8(16, vc) ACC8(24, vd)
    }
    // NATURAL layout store: row u, cols h*64 + dbase .. +32  (wave covers whole 4KB row)
    u16* orow = O + (size_t)u * 2048 + h * 64 + dbase;
    uint4* op = (uint4*)orow;
#pragma unroll
    for (int cc = 0; cc < 4; ++cc) {
        uint4 t;
        t.x = pack2(o[cc * 8 + 0], o[cc * 8 + 1]);
        t.y = pack2(o[cc * 8 + 2], o[cc * 8 + 3]);
        t.z = pack2(o[cc * 8 + 4], o[cc * 8 + 5]);
        t.w = pack2(o[cc * 8 + 6], o[cc * 8 + 7]);
        op[cc] = t;
    }
}

extern "C" void kernel_launch(void* const* d_in, const int* in_sizes, int n_in,
                              void* d_out, int out_size, void* d_ws, size_t ws_size,
                              hipStream_t stream) {
    const float* x = (const float*)d_in[0];
    const float* Wq = (const float*)d_in[1];
    const float* bq = (const float*)d_in[2];
    const float* Wk = (const float*)d_in[3];
    const float* bk = (const float*)d_in[4];
    const float* Wv = (const float*)d_in[5];
    const float* bv = (const float*)d_in[6];
    const float* Wo = (const float*)d_in[7];
    const float* bo = (const float*)d_in[8];

    const size_t MN = (size_t)16384 * 2048;
    const size_t DD = (size_t)2048 * 2048;
    u16* ws = (u16*)d_ws;
    u16* xb = ws;            // bf16 x; reused as attention output after qkv_gemm
    u16* q = ws + MN;
    u16* k = ws + 2 * MN;
    u16* v = ws + 3 * MN;
    u16* wb = ws + 4 * MN;   // 4 bf16 weight matrices, DD each
    u16* ao = xb;            // alias: xb dead after qkv_gemm; NATURAL layout [16384][2048]
    float* out = (float*)d_out;

    dim3 blk(256, 1, 1);
    hipLaunchKernelGGL(cvt5, dim3(4096, 5, 1), blk, 0, stream, x, Wq, Wk, Wv, Wo, xb, wb);
    hipLaunchKernelGGL(qkv_gemm, dim3(16, 128, 3), blk, 0, stream,
                       xb, wb, bq, bk, bv, q, k, v);
    hipLaunchKernelGGL(attn_heads, dim3(4096, 1, 1), blk, 0, stream, q, k, v, ao);
    hipLaunchKernelGGL(out_gemm, dim3(16, 128, 1), blk, 0, stream, ao, wb + 3 * DD, bo, out);
}